// Round 10
// baseline (64.715 us; speedup 1.0000x reference)
//
#include <hip/hip_runtime.h>
#include <stdint.h>
#include <type_traits>

// DCN forward: B=4, H=128, W=128, G=8, C=32, K=8
// inputs      [B,H,W,G,C]   fp32
// deformables [B,H,W,G,K,2] fp32
// weights     [B,H,W,G,K]   fp32
// out         [B,H,W,G,C]   fp32
//
// R10 = R8 skeleton with both pipes thinned (R9's LDS-param dedup regressed:
// it cut VALU 80->36% but added +50% LDS instrs; both pipes are co-binding).
//  - f16 tile (RTN casts at staging): ds_read_b64 gathers, half the LDS bytes.
//    FMA via fma(fpext(f16), f32, f32) -> v_fma_mix_f32 (LLVM mad-mix).
//  - staging clamp == reference image clamp, so in-halo gathers use UNCLAMPED
//    fx,fy: one address (fy<<4)+fx+ub, corners at ds offset imm +1/+16/+17.
//  - interior blocks (wt,ht in [1,14], 76.6%) skip the 8 bounds-mask ops/k
//    (block-uniform branch; in-halo + interior => masks provably all-1).
//  - 8 lanes/pixel, [slot8][PITCH=257] 8B-unit planes: 257 odd -> the 8-lane
//    b64 phase hits 8 distinct bank-pairs mod 16: conflict-free.
//  - rare (!inh, |d|>=4) fallback: exact f32 global gather, reference clamps.

#define Bc 4
#define Hc 128
#define Wc 128
#define Gc 8
#define Kc 8
#define TH 8
#define TW 8
#define RH 4
#define WN 16
#define PITCH 257          // 8B units per slot plane (odd)

typedef float    float4v __attribute__((ext_vector_type(4)));
typedef _Float16 half4v  __attribute__((ext_vector_type(4)));

__global__ __launch_bounds__(512, 8) void dcn_fwd(
    const float* __restrict__ inp,
    const float* __restrict__ def,
    const float* __restrict__ wts,
    float* __restrict__ out)
{
    const int tid = threadIdx.x;
    const int c4  = tid & 7;      // slot: 4 channels
    const int px  = tid >> 3;     // 0..63 pixel in tile
    const int pw  = px & 7;
    const int ph  = px >> 3;

    // grid: wt(16), ht(16), g(8), b(4)
    const int blk = blockIdx.x;
    const int wt = blk & 15;
    const int ht = (blk >> 4) & 15;
    const int g  = (blk >> 8) & 7;
    const int b  = blk >> 11;

    const int h0 = ht * TH, w0 = wt * TW;
    const int row0 = h0 - RH, col0 = w0 - RH;   // window origin (may be <0)

    // global plane as float4 units: index = y*8192 + x*64 + u
    const float4v* gp4 = (const float4v*)((const char*)inp
        + ((size_t)b << 24) + ((size_t)g << 7));

    __shared__ half4v tile[8 * PITCH];   // 16448 B

    // ---- stage 16x16 cell window as f16, [slot][PITCH] 8B units ----
#pragma unroll
    for (int r = 0; r < 4; ++r) {
        const int idx  = r * 512 + tid;          // 2048 units total
        const int cell = idx >> 3;
        const int u    = idx & 7;
        const int rr   = cell >> 4;
        const int cc   = cell & 15;
        const int gr   = min(max(row0 + rr, 0), Hc - 1);
        const int gc   = min(max(col0 + cc, 0), Wc - 1);
        const float4v v = gp4[gr * 8192 + gc * 64 + u];
        const half4v hh = {(_Float16)v.x, (_Float16)v.y,
                           (_Float16)v.z, (_Float16)v.w};
        tile[u * PITCH + cell] = hh;
    }
    __syncthreads();

    const int h = h0 + ph;
    const int w = w0 + pw;
    const int pg = ((b * Hc + h) * Wc + w) * Gc + g;

    // vectorized def/wts loads
    const float4v d0 = *(const float4v*)(def + (size_t)pg * 16 + 0);
    const float4v d1 = *(const float4v*)(def + (size_t)pg * 16 + 4);
    const float4v d2 = *(const float4v*)(def + (size_t)pg * 16 + 8);
    const float4v d3 = *(const float4v*)(def + (size_t)pg * 16 + 12);
    const float4v q0 = *(const float4v*)(wts + (size_t)pg * 8 + 0);
    const float4v q1 = *(const float4v*)(wts + (size_t)pg * 8 + 4);

    const float dxs[8] = {d0.x, d0.z, d1.x, d1.z, d2.x, d2.z, d3.x, d3.z};
    const float dys[8] = {d0.y, d0.w, d1.y, d1.w, d2.y, d2.w, d3.y, d3.w};
    const float wks[8] = {q0.x, q0.y, q0.z, q0.w, q1.x, q1.y, q1.z, q1.w};

    const float wf = (float)w;
    const float hf = (float)h;

    // tile unit index = c4*PITCH + (fy-row0)*16 + (fx-col0) = ub + (fy<<4)+fx
    const int ub = c4 * PITCH - (row0 << 4) - col0;

    float4v acc0 = {0.f, 0.f, 0.f, 0.f};
    float4v acc1 = {0.f, 0.f, 0.f, 0.f};

    auto kloop = [&](auto masked_t) {
        constexpr bool MASKED = decltype(masked_t)::value;
#pragma unroll
        for (int k = 0; k < Kc; ++k) {
            const float dx = dxs[k];
            const float dy = dys[k];
            const float wk = wks[k];

            const float x = dx + wf;
            const float y = dy + hf;

            // truncation toward zero, matching .astype(int32)
            const int fx = (int)x;
            const int fy = (int)y;

            const float wx1 = x - (float)fx;   // exact
            const float wy1 = y - (float)fy;
            const float wx0 = 1.0f - wx1;      // == cxf - x
            const float wy0 = 1.0f - wy1;

            const bool inh = (fabsf(dx) < 4.0f) & (fabsf(dy) < 4.0f);
            if (__builtin_expect(inh, 1)) {
                float ax0 = wx0, ax1 = wx1, ay0 = wy0, ay1 = wy1;
                if constexpr (MASKED) {
                    ax0 = ((uint32_t)fx       < (uint32_t)Wc) ? wx0 : 0.f;
                    ax1 = ((uint32_t)(fx + 1) < (uint32_t)Wc) ? wx1 : 0.f;
                    ay0 = ((uint32_t)fy       < (uint32_t)Hc) ? wy0 : 0.f;
                    ay1 = ((uint32_t)(fy + 1) < (uint32_t)Hc) ? wy1 : 0.f;
                }
                const float ay0k = wk * ay0;
                const float ay1k = wk * ay1;
                const float c00 = ay0k * ax0;
                const float c01 = ay0k * ax1;
                const float c10 = ay1k * ax0;
                const float c11 = ay1k * ax1;

                // unclamped fx,fy valid: |dx|<4 => fx-col0 in [0,15]; staging
                // clamp already equals the reference image clamp.
                const int i00 = ub + (fy << 4) + fx;
                const half4v v00 = tile[i00];
                const half4v v01 = tile[i00 + 1];
                const half4v v10 = tile[i00 + 16];
                const half4v v11 = tile[i00 + 17];

                acc0.x += c00 * (float)v00.x;
                acc0.y += c00 * (float)v00.y;
                acc0.z += c00 * (float)v00.z;
                acc0.w += c00 * (float)v00.w;
                acc1.x += c01 * (float)v01.x;
                acc1.y += c01 * (float)v01.y;
                acc1.z += c01 * (float)v01.z;
                acc1.w += c01 * (float)v01.w;
                acc0.x += c10 * (float)v10.x;
                acc0.y += c10 * (float)v10.y;
                acc0.z += c10 * (float)v10.z;
                acc0.w += c10 * (float)v10.w;
                acc1.x += c11 * (float)v11.x;
                acc1.y += c11 * (float)v11.y;
                acc1.z += c11 * (float)v11.z;
                acc1.w += c11 * (float)v11.w;
            } else {
                // rare: exact f32 global gather with true reference clamps
                const float ax0 = ((uint32_t)fx       < (uint32_t)Wc) ? wx0 : 0.f;
                const float ax1 = ((uint32_t)(fx + 1) < (uint32_t)Wc) ? wx1 : 0.f;
                const float ay0 = ((uint32_t)fy       < (uint32_t)Hc) ? wy0 : 0.f;
                const float ay1 = ((uint32_t)(fy + 1) < (uint32_t)Hc) ? wy1 : 0.f;
                const int xf = min(max(fx,     0), Wc - 1);
                const int xc = min(max(fx + 1, 0), Wc - 1);
                const int yf = min(max(fy,     0), Hc - 1);
                const int yc = min(max(fy + 1, 0), Hc - 1);
                const float ay0k = wk * ay0;
                const float ay1k = wk * ay1;
                const float c00 = ay0k * ax0;
                const float c01 = ay0k * ax1;
                const float c10 = ay1k * ax0;
                const float c11 = ay1k * ax1;
                acc0 += c00 * gp4[yf * 8192 + xf * 64 + c4];
                acc1 += c01 * gp4[yf * 8192 + xc * 64 + c4];
                acc0 += c10 * gp4[yc * 8192 + xf * 64 + c4];
                acc1 += c11 * gp4[yc * 8192 + xc * 64 + c4];
            }
        }
    };

    // interior blocks: in-halo corners provably in-image -> masks all 1
    const bool interior = ((uint32_t)(wt - 1) <= 13u) & ((uint32_t)(ht - 1) <= 13u);
    if (interior) kloop(std::integral_constant<bool, false>{});
    else          kloop(std::integral_constant<bool, true>{});

    const float4v acc = acc0 + acc1;
    ((float4v*)((char*)out + (size_t)pg * 128))[c4] = acc;
}

extern "C" void kernel_launch(void* const* d_in, const int* in_sizes, int n_in,
                              void* d_out, int out_size, void* d_ws, size_t ws_size,
                              hipStream_t stream) {
    const float* inp = (const float*)d_in[0];
    const float* def = (const float*)d_in[1];
    const float* wts = (const float*)d_in[2];
    float* out = (float*)d_out;

    const int nblocks = Bc * Gc * (Hc / TH) * (Wc / TW);  // 8192
    dcn_fwd<<<nblocks, 512, 0, stream>>>(inp, def, wts, out);
}

// Round 11
// 56.714 us; speedup vs baseline: 1.1411x; 1.1411x over previous
//
#include <hip/hip_runtime.h>
#include <stdint.h>
#include <type_traits>

// DCN forward: B=4, H=128, W=128, G=8, C=32, K=8
// inputs      [B,H,W,G,C]   fp32
// deformables [B,H,W,G,K,2] fp32
// weights     [B,H,W,G,K]   fp32
// out         [B,H,W,G,C]   fp32
//
// R11: 1 thread = 1 pixel-group (ALL 32 channels).
//  Rationale: coord math (~39 wave-insts/k) previously served only 8 px/wave
//  (8 lanes/px); now it serves 64 px/wave -> ~8x cut of the dominant VALU
//  term. FMA + LDS bytes per pixel are mapping-invariant.
//  - block 256 thr = 16x16 px tile of one (b,g); halo RH=4 -> 24x24 cells.
//  - f16 tile, cell = 5 half8 units (80 B): odd unit stride -> staging writes
//    conflict-free; gather phases spread across all 8 bank groups.
//  - per k: ONE LDS base addr, 16 ds_read_b128 at imm offsets {0,5,120,125}+u,
//    128 fma (f16 src, f32 acc).
//  - interior tiles (36/64) elide bounds masks; unclamped-index/staging-clamp
//    equivalence as proven in R10; |d|>=4 fallback = exact f32 global gather.

#define Bc 4
#define Hc 128
#define Wc 128
#define Gc 8
#define Kc 8
#define TPX 16
#define RH 4
#define WN 24            // 24x24 cell window
#define NCELL (WN*WN)    // 576
#define CUNITS 5         // half8 units per cell (80 B, 64 used)

typedef float    float4v __attribute__((ext_vector_type(4)));
typedef _Float16 half8v  __attribute__((ext_vector_type(8)));

__global__ __launch_bounds__(256, 3) void dcn_fwd(
    const float* __restrict__ inp,
    const float* __restrict__ def,
    const float* __restrict__ wts,
    float* __restrict__ out)
{
    const int tid = threadIdx.x;
    const int pw  = tid & 15;
    const int ph  = tid >> 4;

    // grid: wt(8), ht(8), g(8), b(4)
    const int blk = blockIdx.x;
    const int wt = blk & 7;
    const int ht = (blk >> 3) & 7;
    const int g  = (blk >> 6) & 7;
    const int b  = blk >> 9;

    const int h0 = ht * TPX, w0 = wt * TPX;
    const int row0 = h0 - RH, col0 = w0 - RH;   // window origin (may be <0)

    // global plane as float4 units: index = y*8192 + x*64 + u
    const float4v* gp4 = (const float4v*)((const char*)inp
        + ((size_t)b << 24) + ((size_t)g << 7));

    __shared__ half8v tile[NCELL * CUNITS];   // 46080 B

    // ---- stage 24x24 cell window as f16 (RTN), conflict-free writes ----
    for (int cell = tid; cell < NCELL; cell += 256) {
        const int rr = (cell * 2731) >> 16;       // exact cell/24 for cell<576
        const int cc = cell - rr * WN;
        const int gr = min(max(row0 + rr, 0), Hc - 1);
        const int gc = min(max(col0 + cc, 0), Wc - 1);
        const float4v* src = &gp4[gr * 8192 + gc * 64];
#pragma unroll
        for (int u2 = 0; u2 < 4; ++u2) {
            const float4v a = src[u2 * 2];
            const float4v c = src[u2 * 2 + 1];
            const half8v hv = {(_Float16)a.x, (_Float16)a.y,
                               (_Float16)a.z, (_Float16)a.w,
                               (_Float16)c.x, (_Float16)c.y,
                               (_Float16)c.z, (_Float16)c.w};
            tile[cell * CUNITS + u2] = hv;
        }
    }
    __syncthreads();

    const int h = h0 + ph;
    const int w = w0 + pw;
    const int pg = ((b * Hc + h) * Wc + w) * Gc + g;

    // per-pixel def/wts (scattered b128 loads; ~1 KB lane stride)
    const float4v d0 = *(const float4v*)(def + (size_t)pg * 16 + 0);
    const float4v d1 = *(const float4v*)(def + (size_t)pg * 16 + 4);
    const float4v d2 = *(const float4v*)(def + (size_t)pg * 16 + 8);
    const float4v d3 = *(const float4v*)(def + (size_t)pg * 16 + 12);
    const float4v q0 = *(const float4v*)(wts + (size_t)pg * 8 + 0);
    const float4v q1 = *(const float4v*)(wts + (size_t)pg * 8 + 4);

    const float dxs[8] = {d0.x, d0.z, d1.x, d1.z, d2.x, d2.z, d3.x, d3.z};
    const float dys[8] = {d0.y, d0.w, d1.y, d1.w, d2.y, d2.w, d3.y, d3.w};
    const float wks[8] = {q0.x, q0.y, q0.z, q0.w, q1.x, q1.y, q1.z, q1.w};

    const float wf = (float)w;
    const float hf = (float)h;

    float acc[32];
#pragma unroll
    for (int i = 0; i < 32; ++i) acc[i] = 0.f;

    auto kloop = [&](auto masked_t) {
        constexpr bool MASKED = decltype(masked_t)::value;
#pragma unroll
        for (int k = 0; k < Kc; ++k) {
            const float dx = dxs[k];
            const float dy = dys[k];
            const float wk = wks[k];

            const float x = dx + wf;
            const float y = dy + hf;

            // truncation toward zero, matching .astype(int32)
            const int fx = (int)x;
            const int fy = (int)y;

            const float wx1 = x - (float)fx;   // exact
            const float wy1 = y - (float)fy;
            const float wx0 = 1.0f - wx1;      // == cxf - x
            const float wy0 = 1.0f - wy1;

            const bool inh = (fabsf(dx) < 4.0f) & (fabsf(dy) < 4.0f);
            if (__builtin_expect(inh, 1)) {
                float ax0 = wx0, ax1 = wx1, ay0 = wy0, ay1 = wy1;
                if constexpr (MASKED) {
                    ax0 = ((uint32_t)fx       < (uint32_t)Wc) ? wx0 : 0.f;
                    ax1 = ((uint32_t)(fx + 1) < (uint32_t)Wc) ? wx1 : 0.f;
                    ay0 = ((uint32_t)fy       < (uint32_t)Hc) ? wy0 : 0.f;
                    ay1 = ((uint32_t)(fy + 1) < (uint32_t)Hc) ? wy1 : 0.f;
                }
                const float ay0k = wk * ay0;
                const float ay1k = wk * ay1;
                const float c00 = ay0k * ax0;
                const float c01 = ay0k * ax1;
                const float c10 = ay1k * ax0;
                const float c11 = ay1k * ax1;

                // unclamped fx,fy valid in-window (|d|<4); staging clamp
                // already equals the reference image clamp.
                const int ib = ((fy - row0) * WN + (fx - col0)) * CUNITS;
#pragma unroll
                for (int u = 0; u < 4; ++u) {
                    const half8v v00 = tile[ib + u];            // (x  ,y  )
                    const half8v v01 = tile[ib + CUNITS + u];   // (x+1,y  )
                    const half8v v10 = tile[ib + WN*CUNITS + u];        // (x,y+1)
                    const half8v v11 = tile[ib + (WN+1)*CUNITS + u];    // (x+1,y+1)
#pragma unroll
                    for (int j = 0; j < 8; ++j) {
                        float s = acc[u * 8 + j];
                        s = fmaf((float)v00[j], c00, s);
                        s = fmaf((float)v01[j], c01, s);
                        s = fmaf((float)v10[j], c10, s);
                        s = fmaf((float)v11[j], c11, s);
                        acc[u * 8 + j] = s;
                    }
                }
            } else {
                // rare: exact f32 global gather with true reference semantics
                const float ax0 = ((uint32_t)fx       < (uint32_t)Wc) ? wx0 : 0.f;
                const float ax1 = ((uint32_t)(fx + 1) < (uint32_t)Wc) ? wx1 : 0.f;
                const float ay0 = ((uint32_t)fy       < (uint32_t)Hc) ? wy0 : 0.f;
                const float ay1 = ((uint32_t)(fy + 1) < (uint32_t)Hc) ? wy1 : 0.f;
                const int xf = min(max(fx,     0), Wc - 1);
                const int xc = min(max(fx + 1, 0), Wc - 1);
                const int yf = min(max(fy,     0), Hc - 1);
                const int yc = min(max(fy + 1, 0), Hc - 1);
                const float ay0k = wk * ay0;
                const float ay1k = wk * ay1;
                const float c00 = ay0k * ax0;
                const float c01 = ay0k * ax1;
                const float c10 = ay1k * ax0;
                const float c11 = ay1k * ax1;
                const float4v* p00 = &gp4[yf * 8192 + xf * 64];
                const float4v* p01 = &gp4[yf * 8192 + xc * 64];
                const float4v* p10 = &gp4[yc * 8192 + xf * 64];
                const float4v* p11 = &gp4[yc * 8192 + xc * 64];
#pragma unroll
                for (int u2 = 0; u2 < 8; ++u2) {
                    const float4v a = p00[u2], bb = p01[u2];
                    const float4v c = p10[u2], dd = p11[u2];
#pragma unroll
                    for (int e = 0; e < 4; ++e) {
                        float s = acc[u2 * 4 + e];
                        s = fmaf(a[e],  c00, s);
                        s = fmaf(bb[e], c01, s);
                        s = fmaf(c[e],  c10, s);
                        s = fmaf(dd[e], c11, s);
                        acc[u2 * 4 + e] = s;
                    }
                }
            }
        }
    };

    // interior tiles: in-halo corners provably in-image -> masks all 1
    const bool interior = ((uint32_t)(wt - 1) <= 5u) & ((uint32_t)(ht - 1) <= 5u);
    if (interior) kloop(std::integral_constant<bool, false>{});
    else          kloop(std::integral_constant<bool, true>{});

    float4v* op = (float4v*)((char*)out + (size_t)pg * 128);
#pragma unroll
    for (int u2 = 0; u2 < 8; ++u2) {
        float4v o = {acc[u2*4], acc[u2*4+1], acc[u2*4+2], acc[u2*4+3]};
        op[u2] = o;
    }
}

extern "C" void kernel_launch(void* const* d_in, const int* in_sizes, int n_in,
                              void* d_out, int out_size, void* d_ws, size_t ws_size,
                              hipStream_t stream) {
    const float* inp = (const float*)d_in[0];
    const float* def = (const float*)d_in[1];
    const float* wts = (const float*)d_in[2];
    float* out = (float*)d_out;

    const int nblocks = Bc * Gc * (Hc / TPX) * (Wc / TPX);  // 2048
    dcn_fwd<<<nblocks, 256, 0, stream>>>(inp, def, wts, out);
}